// Round 15
// baseline (264.210 us; speedup 1.0000x reference)
//
#include <hip/hip_runtime.h>

#define BIGV 1e10f
constexpr float INV_LN2   = 1.4426950408889634f;
constexpr float T_INV_LN2 = 2.8853900817779268f;   // 2/ln2
constexpr float LN2f      = 0.6931471805599453f;

// Fused soft-DTW: log2-domain wavefront DP (r10-proven schedule) with the
// squared-distance computed on the fly in the issue slack of the softmin
// latency chain. Wave w owns rows 64w+1..64w+64; lane l row 64w+l+1; step t:
// lane l at col j = t-l. Cross-lane: DPP wf_sr1. Cross-wave: LDS ring, lag-5
// phases of K=16; guarded edge phases; 15-step peel; lgkm-only barrier.
// nd(r,j) = -|x_r - y_j|^2/ln2 = dot(x*2/ln2, y) + (-|x|^2/ln2) + (-|y|^2/ln2),
// with x pre-scaled in regs, y rows rolling in 4 register slots (4-step
// prefetch, L1-resident), and -|y|^2/ln2 staged once in LDS.
__global__ __launch_bounds__(512, 1) void dp_kernel(
    const float* __restrict__ X, const float* __restrict__ Y,
    float* __restrict__ out)
{
  const int b   = blockIdx.x;
  const int tid = threadIdx.x;
  const int w   = tid >> 6;
  const int l   = tid & 63;
  const int r   = 64 * w + l;

  __shared__ alignas(16) float ring[8][64];   // rows 0..6 = boundaries, 7 = dump
  __shared__ float y2n[512];                  // -|y_j|^2 / ln2

  const float*  yb  = Y + (size_t)b * 8192;
  const float4* yb4 = (const float4*)yb;

  // ---- stage y2n ----
  {
    const float4* p = yb4 + (size_t)tid * 4;
    float4 v0 = p[0], v1 = p[1], v2 = p[2], v3 = p[3];
    float s = 0.f;
    s=fmaf(v0.x,v0.x,s); s=fmaf(v0.y,v0.y,s); s=fmaf(v0.z,v0.z,s); s=fmaf(v0.w,v0.w,s);
    s=fmaf(v1.x,v1.x,s); s=fmaf(v1.y,v1.y,s); s=fmaf(v1.z,v1.z,s); s=fmaf(v1.w,v1.w,s);
    s=fmaf(v2.x,v2.x,s); s=fmaf(v2.y,v2.y,s); s=fmaf(v2.z,v2.z,s); s=fmaf(v2.w,v2.w,s);
    s=fmaf(v3.x,v3.x,s); s=fmaf(v3.y,v3.y,s); s=fmaf(v3.z,v3.z,s); s=fmaf(v3.w,v3.w,s);
    y2n[tid] = -s * INV_LN2;
  }

  // ---- x row r: xr scaled by 2/ln2; cx = -|x|^2/ln2 ----
  float xr[16]; float cx;
  {
    const float4* px = (const float4*)(X + ((size_t)b * 512 + r) * 16);
    float4 u0 = px[0], u1 = px[1], u2 = px[2], u3 = px[3];
    float tv[16] = { u0.x,u0.y,u0.z,u0.w, u1.x,u1.y,u1.z,u1.w,
                     u2.x,u2.y,u2.z,u2.w, u3.x,u3.y,u3.z,u3.w };
    float s = 0.f;
    #pragma unroll
    for (int q = 0; q < 16; ++q) { s = fmaf(tv[q], tv[q], s); xr[q] = tv[q] * T_INV_LN2; }
    cx = -s * INV_LN2;
  }

  float P  = BIGV;
  float dg = (w == 0 && l == 0) ? 0.f : BIGV;
  const bool doring = (l == 63) && (w < 7);

  __syncthreads();   // y2n ready

  // ---- rolling y slots: step t uses row t-1-l; slot = (t-1) mod 4 ----
  float4 Ya0,Ya1,Ya2,Ya3, Yb0,Yb1,Yb2,Yb3, Yc0,Yc1,Yc2,Yc3, Yd0,Yd1,Yd2,Yd3;
  float ga, gb, gc, gd;
#define INITSLOT(S, Y0,Y1,Y2,Y3, G) { int jc_ = (S) - l; jc_ = jc_ < 0 ? 0 : jc_; \
    const float4* p_ = yb4 + (size_t)jc_ * 4; \
    Y0 = p_[0]; Y1 = p_[1]; Y2 = p_[2]; Y3 = p_[3]; G = y2n[jc_]; }
  INITSLOT(0, Ya0,Ya1,Ya2,Ya3, ga)
  INITSLOT(1, Yb0,Yb1,Yb2,Yb3, gb)
  INITSLOT(2, Yc0,Yc1,Yc2,Yc3, gc)
  INITSLOT(3, Yd0,Yd1,Yd2,Yd3, gd)
#undef INITSLOT

#define NDDOT(Y0,Y1,Y2,Y3, GV)                                                 \
    float s0_ = fmaf(xr[0], Y0.x, fmaf(xr[4], Y1.x, fmaf(xr[8],  Y2.x, xr[12]*Y3.x))); \
    float s1_ = fmaf(xr[1], Y0.y, fmaf(xr[5], Y1.y, fmaf(xr[9],  Y2.y, xr[13]*Y3.y))); \
    float s2_ = fmaf(xr[2], Y0.z, fmaf(xr[6], Y1.z, fmaf(xr[10], Y2.z, xr[14]*Y3.z))); \
    float s3_ = fmaf(xr[3], Y0.w, fmaf(xr[7], Y1.w, fmaf(xr[11], Y2.w, xr[15]*Y3.w))); \
    const float nd_ = ((s0_ + s1_) + (s2_ + s3_)) + (cx + (GV));

#define CELLCORE(RV)                                                           \
    const int sp_ = __builtin_amdgcn_update_dpp(__builtin_bit_cast(int, P),    \
        __builtin_bit_cast(int, P), 0x138, 0xF, 0xF, false);                   \
    float up_ = __builtin_bit_cast(float, sp_);                                \
    if (l == 0) up_ = (w == 0) ? BIGV : (RV);                                  \
    const float mn_ = fminf(fminf(dg, up_), P);                                \
    const float se_ = __builtin_amdgcn_exp2f(mn_ - dg)                         \
                    + __builtin_amdgcn_exp2f(mn_ - up_)                        \
                    + __builtin_amdgcn_exp2f(mn_ - P);                         \
    float c_ = mn_ - __builtin_amdgcn_logf(se_) - nd_;

// FAST: interior phases (pw 4..30): unclamped prefetch, base+imm addressing
#define DPSTEP_F(K, Y0,Y1,Y2,Y3, GV, RV)                                       \
  {                                                                            \
    NDDOT(Y0,Y1,Y2,Y3, GV)                                                     \
    { const float4* py_ = ybph4 + (size_t)(K) * 4;                             \
      Y0 = py_[0]; Y1 = py_[1]; Y2 = py_[2]; Y3 = py_[3]; GV = y2ph[K]; }      \
    CELLCORE(RV)                                                               \
    dg = up_; P = c_;                                                          \
    if (doring) ring[w][(tb64 + (K)) & 63] = c_;                               \
  }

// SAFE: edge phases & peel: clamped prefetch + validity guard
#define DPSTEP_S(K, Y0,Y1,Y2,Y3, GV, RV)                                       \
  {                                                                            \
    NDDOT(Y0,Y1,Y2,Y3, GV)                                                     \
    { int jn_ = tml + (K) + 4; jn_ = jn_ < 0 ? 0 : (jn_ > 511 ? 511 : jn_);    \
      const float4* py_ = yb4 + (size_t)jn_ * 4;                               \
      Y0 = py_[0]; Y1 = py_[1]; Y2 = py_[2]; Y3 = py_[3]; GV = y2n[jn_]; }     \
    CELLCORE(RV)                                                               \
    c_ = ((unsigned)(tml + (K)) < 512u) ? c_ : BIGV;                           \
    dg = up_; P = c_;                                                          \
    if (doring) ring[w][(tb64 + (K)) & 63] = c_;                               \
  }

#define DP16_F                                                                 \
    DPSTEP_F(0,  Ya0,Ya1,Ya2,Ya3, ga, rg0.x) DPSTEP_F(1,  Yb0,Yb1,Yb2,Yb3, gb, rg0.y) \
    DPSTEP_F(2,  Yc0,Yc1,Yc2,Yc3, gc, rg0.z) DPSTEP_F(3,  Yd0,Yd1,Yd2,Yd3, gd, rg0.w) \
    DPSTEP_F(4,  Ya0,Ya1,Ya2,Ya3, ga, rg1.x) DPSTEP_F(5,  Yb0,Yb1,Yb2,Yb3, gb, rg1.y) \
    DPSTEP_F(6,  Yc0,Yc1,Yc2,Yc3, gc, rg1.z) DPSTEP_F(7,  Yd0,Yd1,Yd2,Yd3, gd, rg1.w) \
    DPSTEP_F(8,  Ya0,Ya1,Ya2,Ya3, ga, rg2.x) DPSTEP_F(9,  Yb0,Yb1,Yb2,Yb3, gb, rg2.y) \
    DPSTEP_F(10, Yc0,Yc1,Yc2,Yc3, gc, rg2.z) DPSTEP_F(11, Yd0,Yd1,Yd2,Yd3, gd, rg2.w) \
    DPSTEP_F(12, Ya0,Ya1,Ya2,Ya3, ga, rg3.x) DPSTEP_F(13, Yb0,Yb1,Yb2,Yb3, gb, rg3.y) \
    DPSTEP_F(14, Yc0,Yc1,Yc2,Yc3, gc, rg3.z) DPSTEP_F(15, Yd0,Yd1,Yd2,Yd3, gd, rg3.w)

#define DP16_S                                                                 \
    DPSTEP_S(0,  Ya0,Ya1,Ya2,Ya3, ga, rg0.x) DPSTEP_S(1,  Yb0,Yb1,Yb2,Yb3, gb, rg0.y) \
    DPSTEP_S(2,  Yc0,Yc1,Yc2,Yc3, gc, rg0.z) DPSTEP_S(3,  Yd0,Yd1,Yd2,Yd3, gd, rg0.w) \
    DPSTEP_S(4,  Ya0,Ya1,Ya2,Ya3, ga, rg1.x) DPSTEP_S(5,  Yb0,Yb1,Yb2,Yb3, gb, rg1.y) \
    DPSTEP_S(6,  Yc0,Yc1,Yc2,Yc3, gc, rg1.z) DPSTEP_S(7,  Yd0,Yd1,Yd2,Yd3, gd, rg1.w) \
    DPSTEP_S(8,  Ya0,Ya1,Ya2,Ya3, ga, rg2.x) DPSTEP_S(9,  Yb0,Yb1,Yb2,Yb3, gb, rg2.y) \
    DPSTEP_S(10, Yc0,Yc1,Yc2,Yc3, gc, rg2.z) DPSTEP_S(11, Yd0,Yd1,Yd2,Yd3, gd, rg2.w) \
    DPSTEP_S(12, Ya0,Ya1,Ya2,Ya3, ga, rg3.x) DPSTEP_S(13, Yb0,Yb1,Yb2,Yb3, gb, rg3.y) \
    DPSTEP_S(14, Yc0,Yc1,Yc2,Yc3, gc, rg3.z) DPSTEP_S(15, Yd0,Yd1,Yd2,Yd3, gd, rg3.w)

  for (int p = 0; p < 70; ++p) {
    const int pw = p - 5 * w;
    if ((unsigned)pw < 36u) {
      const int tml  = 16 * pw - l;       // j-1 of step K=0 (= tb-l-1, tb=16pw+1)
      const int tb64 = 16 * pw - 63;      // tb - 64 (ring index base)
      const int wi   = (w > 0) ? (w - 1) : 0;
      const float4* rpq = (const float4*)(&ring[wi][0]);
      const int rb = 4 * (pw & 3);
      const float4 rg0 = rpq[rb], rg1 = rpq[rb+1], rg2 = rpq[rb+2], rg3 = rpq[rb+3];
      if ((unsigned)(pw - 4) < 27u) {     // pw 4..30: prefetch rows all in [0,511]
        const float4* ybph4 = yb4 + (size_t)(tml + 4) * 4;
        const float*  y2ph  = &y2n[tml + 4];
        DP16_F
      } else {
        DP16_S
      }
    }
    __builtin_amdgcn_sched_barrier(0);
    asm volatile("s_waitcnt lgkmcnt(0)" ::: "memory");
    __builtin_amdgcn_s_barrier();
    __builtin_amdgcn_sched_barrier(0);
  }

  // peel: wave 7's pw = 35 (tb = 561), steps t = 561..575 only (skip t = 576)
  if (w == 7) {
    const int tml  = 560 - l;
    const int tb64 = 497;
    const float4* rpq = (const float4*)(&ring[6][0]);
    const int rb = 12;                    // 4 * (35 & 3)
    const float4 rg0 = rpq[rb], rg1 = rpq[rb+1], rg2 = rpq[rb+2], rg3 = rpq[rb+3];
    DPSTEP_S(0,  Ya0,Ya1,Ya2,Ya3, ga, rg0.x) DPSTEP_S(1,  Yb0,Yb1,Yb2,Yb3, gb, rg0.y)
    DPSTEP_S(2,  Yc0,Yc1,Yc2,Yc3, gc, rg0.z) DPSTEP_S(3,  Yd0,Yd1,Yd2,Yd3, gd, rg0.w)
    DPSTEP_S(4,  Ya0,Ya1,Ya2,Ya3, ga, rg1.x) DPSTEP_S(5,  Yb0,Yb1,Yb2,Yb3, gb, rg1.y)
    DPSTEP_S(6,  Yc0,Yc1,Yc2,Yc3, gc, rg1.z) DPSTEP_S(7,  Yd0,Yd1,Yd2,Yd3, gd, rg1.w)
    DPSTEP_S(8,  Ya0,Ya1,Ya2,Ya3, ga, rg2.x) DPSTEP_S(9,  Yb0,Yb1,Yb2,Yb3, gb, rg2.y)
    DPSTEP_S(10, Yc0,Yc1,Yc2,Yc3, gc, rg2.z) DPSTEP_S(11, Yd0,Yd1,Yd2,Yd3, gd, rg2.w)
    DPSTEP_S(12, Ya0,Ya1,Ya2,Ya3, ga, rg3.x) DPSTEP_S(13, Yb0,Yb1,Yb2,Yb3, gb, rg3.y)
    DPSTEP_S(14, Yc0,Yc1,Yc2,Yc3, gc, rg3.z)
  }
#undef DP16_F
#undef DP16_S
#undef DPSTEP_F
#undef DPSTEP_S
#undef CELLCORE
#undef NDDOT

  if (tid == 511) out[b] = P * LN2f;   // P = r'(512,512) in log2 units
}

extern "C" void kernel_launch(void* const* d_in, const int* in_sizes, int n_in,
                              void* d_out, int out_size, void* d_ws, size_t ws_size,
                              hipStream_t stream)
{
  const float* x = (const float*)d_in[0];
  const float* y = (const float*)d_in[1];
  float* o = (float*)d_out;
  dp_kernel<<<64, 512, 0, stream>>>(x, y, o);
}

// Round 16
// 121.146 us; speedup vs baseline: 2.1809x; 2.1809x over previous
//
#include <hip/hip_runtime.h>

#define BIGV 1e10f
constexpr float INV_LN2 = 1.4426950408889634f;
constexpr float LN2f    = 0.6931471805599453f;

// ---------------- Phase 1: ND[b][r][e] f16, stride 516 elems ----------------
// Row r holds nd(r,jy) = -|x_r - y_jy|^2/ln2 at elem e = jy + (r&3); e outside
// [r&3, 511+(r&3)] = -60000 guards. v2: register ping-pong prefetch of x rows
// (LDS latency hidden under the 2-row FMA block), direct float4 FMAs.
__global__ __launch_bounds__(256) void dist_kernel(
    const float* __restrict__ X, const float* __restrict__ Y,
    unsigned short* __restrict__ ND)
{
  const int b  = blockIdx.x;
  const int jg = blockIdx.y;            // 8 j-groups of 64
  const int t  = threadIdx.x;
  const int wv = t >> 6, lane = t & 63;
  const int jy = 64 * jg + lane;

  __shared__ float4 xsh4[2048];         // x rows, 32 KB
  __shared__ float  x2sh[512];

  const float*  xb  = X + (size_t)b * 8192;
  const float4* xb4 = (const float4*)xb;
  const float*  yb  = Y + (size_t)b * 8192;

  for (int i = t; i < 2048; i += 256) xsh4[i] = xb4[i];

  {
    const float4* p = (const float4*)(xb + (size_t)(2 * t) * 16);
    float4 a0=p[0],a1=p[1],a2=p[2],a3=p[3], c0=p[4],c1=p[5],c2=p[6],c3=p[7];
    float sa = 0.f, sc = 0.f;
    sa=fmaf(a0.x,a0.x,sa); sa=fmaf(a0.y,a0.y,sa); sa=fmaf(a0.z,a0.z,sa); sa=fmaf(a0.w,a0.w,sa);
    sa=fmaf(a1.x,a1.x,sa); sa=fmaf(a1.y,a1.y,sa); sa=fmaf(a1.z,a1.z,sa); sa=fmaf(a1.w,a1.w,sa);
    sa=fmaf(a2.x,a2.x,sa); sa=fmaf(a2.y,a2.y,sa); sa=fmaf(a2.z,a2.z,sa); sa=fmaf(a2.w,a2.w,sa);
    sa=fmaf(a3.x,a3.x,sa); sa=fmaf(a3.y,a3.y,sa); sa=fmaf(a3.z,a3.z,sa); sa=fmaf(a3.w,a3.w,sa);
    sc=fmaf(c0.x,c0.x,sc); sc=fmaf(c0.y,c0.y,sc); sc=fmaf(c0.z,c0.z,sc); sc=fmaf(c0.w,c0.w,sc);
    sc=fmaf(c1.x,c1.x,sc); sc=fmaf(c1.y,c1.y,sc); sc=fmaf(c1.z,c1.z,sc); sc=fmaf(c1.w,c1.w,sc);
    sc=fmaf(c2.x,c2.x,sc); sc=fmaf(c2.y,c2.y,sc); sc=fmaf(c2.z,c2.z,sc); sc=fmaf(c2.w,c2.w,sc);
    sc=fmaf(c3.x,c3.x,sc); sc=fmaf(c3.y,c3.y,sc); sc=fmaf(c3.z,c3.z,sc); sc=fmaf(c3.w,c3.w,sc);
    x2sh[2 * t] = sa; x2sh[2 * t + 1] = sc;
  }

  float4 yq0, yq1, yq2, yq3; float y2 = 0.f;
  {
    const float4* p = (const float4*)(yb + (size_t)jy * 16);
    yq0 = p[0]; yq1 = p[1]; yq2 = p[2]; yq3 = p[3];
    y2=fmaf(yq0.x,yq0.x,y2); y2=fmaf(yq0.y,yq0.y,y2); y2=fmaf(yq0.z,yq0.z,y2); y2=fmaf(yq0.w,yq0.w,y2);
    y2=fmaf(yq1.x,yq1.x,y2); y2=fmaf(yq1.y,yq1.y,y2); y2=fmaf(yq1.z,yq1.z,y2); y2=fmaf(yq1.w,yq1.w,y2);
    y2=fmaf(yq2.x,yq2.x,y2); y2=fmaf(yq2.y,yq2.y,y2); y2=fmaf(yq2.z,yq2.z,y2); y2=fmaf(yq2.w,yq2.w,y2);
    y2=fmaf(yq3.x,yq3.x,y2); y2=fmaf(yq3.y,yq3.y,y2); y2=fmaf(yq3.z,yq3.z,y2); y2=fmaf(yq3.w,yq3.w,y2);
  }
  __syncthreads();

  unsigned short* nb = ND + (size_t)b * 512 * 516;
  const int r0 = 128 * wv;

  // compute rows (r_, r_+1) from float4 regs; writes two f16 elems
  auto comp2 = [&](int r_, float4 A0, float4 A1, float4 A2, float4 A3,
                   float4 C0, float4 C1, float4 C2, float4 C3,
                   float sxa, float sxc) {
    float p0 = A0.x*yq0.x, p1 = A0.y*yq0.y, p2 = A0.z*yq0.z, p3 = A0.w*yq0.w;
    p0=fmaf(A1.x,yq1.x,p0); p1=fmaf(A1.y,yq1.y,p1); p2=fmaf(A1.z,yq1.z,p2); p3=fmaf(A1.w,yq1.w,p3);
    p0=fmaf(A2.x,yq2.x,p0); p1=fmaf(A2.y,yq2.y,p1); p2=fmaf(A2.z,yq2.z,p2); p3=fmaf(A2.w,yq2.w,p3);
    p0=fmaf(A3.x,yq3.x,p0); p1=fmaf(A3.y,yq3.y,p1); p2=fmaf(A3.z,yq3.z,p2); p3=fmaf(A3.w,yq3.w,p3);
    float q0 = C0.x*yq0.x, q1 = C0.y*yq0.y, q2 = C0.z*yq0.z, q3 = C0.w*yq0.w;
    q0=fmaf(C1.x,yq1.x,q0); q1=fmaf(C1.y,yq1.y,q1); q2=fmaf(C1.z,yq1.z,q2); q3=fmaf(C1.w,yq1.w,q3);
    q0=fmaf(C2.x,yq2.x,q0); q1=fmaf(C2.y,yq2.y,q1); q2=fmaf(C2.z,yq2.z,q2); q3=fmaf(C2.w,yq2.w,q3);
    q0=fmaf(C3.x,yq3.x,q0); q1=fmaf(C3.y,yq3.y,q1); q2=fmaf(C3.z,yq3.z,q2); q3=fmaf(C3.w,yq3.w,q3);
    const float nd0 = fmaf(2.f, (p0+p1)+(p2+p3), sxa) * INV_LN2;
    const float nd1 = fmaf(2.f, (q0+q1)+(q2+q3), sxc) * INV_LN2;
    nb[(size_t)r_ * 516 + jy + (r_ & 3)]             = __builtin_bit_cast(unsigned short, (_Float16)nd0);
    nb[(size_t)(r_ + 1) * 516 + jy + ((r_ + 1) & 3)] = __builtin_bit_cast(unsigned short, (_Float16)nd1);
  };

  // prime buffer A with rows r0, r0+1
  const float4* xp = &xsh4[(size_t)r0 * 4];
  float4 A0=xp[0],A1=xp[1],A2=xp[2],A3=xp[3], C0=xp[4],C1=xp[5],C2=xp[6],C3=xp[7];
  float sxa = -(x2sh[r0] + y2), sxc = -(x2sh[r0 + 1] + y2);

  #pragma unroll 4
  for (int rr = 0; rr < 128; rr += 4) {
    // prefetch rows rr+2, rr+3 into buffer B
    const int rn = (rr + 2 < 128) ? rr + 2 : 0;
    const float4* xq = &xsh4[(size_t)(r0 + rn) * 4];
    float4 B0=xq[0],B1=xq[1],B2=xq[2],B3=xq[3], D0=xq[4],D1=xq[5],D2=xq[6],D3=xq[7];
    float sxb = -(x2sh[r0 + rn] + y2), sxd = -(x2sh[r0 + rn + 1] + y2);

    comp2(r0 + rr, A0,A1,A2,A3, C0,C1,C2,C3, sxa, sxc);

    // prefetch rows rr+4, rr+5 into buffer A
    const int rm = (rr + 4 < 128) ? rr + 4 : 0;
    const float4* xm = &xsh4[(size_t)(r0 + rm) * 4];
    A0=xm[0]; A1=xm[1]; A2=xm[2]; A3=xm[3]; C0=xm[4]; C1=xm[5]; C2=xm[6]; C3=xm[7];
    sxa = -(x2sh[r0 + rm] + y2); sxc = -(x2sh[r0 + rm + 1] + y2);

    comp2(r0 + rn, B0,B1,B2,B3, D0,D1,D2,D3, sxb, sxd);
  }

  if (jg == 0) {
    const unsigned short G = __builtin_bit_cast(unsigned short, (_Float16)(-60000.0f));
    #pragma unroll
    for (int rr2 = 0; rr2 < 2; ++rr2) {
      const int r = 2 * t + rr2, sh = r & 3;
      unsigned short* rowp = nb + (size_t)r * 516;
      #pragma unroll
      for (int k = 0; k < 4; ++k) {
        const int e = (k < sh) ? k : 512 + k;
        rowp[e] = G;
      }
    }
  }
}

// ---------------- Phase 2: log2-domain wavefront DP, 8-wave pipeline (r10/r14-proven) ----------------
template<bool PRE>
__global__ __launch_bounds__(512, 1) void dp_kernel(
    const unsigned short* __restrict__ ND, const float* __restrict__ X,
    const float* __restrict__ Y, float* __restrict__ out)
{
  const int b   = blockIdx.x;
  const int tid = threadIdx.x;
  const int w   = tid >> 6;
  const int l   = tid & 63;
  const int r   = 64 * w + l;

  __shared__ alignas(16) float ring[8][64];   // rows 0..6 = boundaries, 7 = dump

  float P  = BIGV;
  float dg = (w == 0 && l == 0) ? 0.f : BIGV;
  const bool doring = (l == 63) && (w < 7);
  const int  lq = l >> 2;

  const uint2* rp = nullptr;
  uint2 cur0, cur1, cur2, cur3, nxt0, nxt1, nxt2, nxt3;
  float xr0[16];
  float x2 = 0.f;
  const float4* yb4 = (const float4*)(Y + (size_t)b * 8192);

  if constexpr (PRE) {
    rp = (const uint2*)(ND + ((size_t)b * 512 + (size_t)r) * 516);
    cur0 = rp[min(max(0 - lq, 0), 128)];
    cur1 = rp[min(max(1 - lq, 0), 128)];
    cur2 = rp[min(max(2 - lq, 0), 128)];
    cur3 = rp[min(max(3 - lq, 0), 128)];
  } else {
    const float4* px = (const float4*)(X + ((size_t)b * 512 + r) * 16);
    float4 u0 = px[0], u1 = px[1], u2 = px[2], u3 = px[3];
    float tv[16] = { u0.x,u0.y,u0.z,u0.w, u1.x,u1.y,u1.z,u1.w,
                     u2.x,u2.y,u2.z,u2.w, u3.x,u3.y,u3.z,u3.w };
    #pragma unroll
    for (int q = 0; q < 16; ++q) { xr0[q] = tv[q]; x2 = fmaf(tv[q], tv[q], x2); }
  }

#define DPSTEP(K, DW, HI, RV, GUARDED)                                         \
  {                                                                            \
    float nd_;                                                                 \
    if constexpr (PRE) {                                                       \
      nd_ = (float)__builtin_bit_cast(_Float16,                                \
              (unsigned short)((HI) ? ((DW) >> 16) : ((DW) & 0xffffu)));       \
    } else {                                                                   \
      const int jy_ = tml + (K);                                               \
      const int jc_ = min(max(jy_, 0), 511);                                   \
      float4 q0 = yb4[4*jc_+0], q1 = yb4[4*jc_+1],                             \
             q2 = yb4[4*jc_+2], q3 = yb4[4*jc_+3];                             \
      float yv_[16] = { q0.x,q0.y,q0.z,q0.w, q1.x,q1.y,q1.z,q1.w,              \
                        q2.x,q2.y,q2.z,q2.w, q3.x,q3.y,q3.z,q3.w };            \
      float y2_ = 0.f, d0_ = 0.f;                                              \
      _Pragma("unroll")                                                        \
      for (int q = 0; q < 16; ++q) {                                           \
        y2_ = fmaf(yv_[q], yv_[q], y2_);                                       \
        d0_ = fmaf(xr0[q], yv_[q], d0_);                                       \
      }                                                                        \
      nd_ = (2.f * d0_ - x2 - y2_) * INV_LN2;                                  \
    }                                                                          \
    const int sp_ = __builtin_amdgcn_update_dpp(__builtin_bit_cast(int, P),    \
        __builtin_bit_cast(int, P), 0x138, 0xF, 0xF, false);                   \
    float up_ = __builtin_bit_cast(float, sp_);                                \
    if (l == 0) up_ = (w == 0) ? BIGV : (RV);                                  \
    const float mn_ = fminf(fminf(dg, up_), P);                                \
    const float s_  = __builtin_amdgcn_exp2f(mn_ - dg)                         \
                    + __builtin_amdgcn_exp2f(mn_ - up_)                        \
                    + __builtin_amdgcn_exp2f(mn_ - P);                         \
    float c_ = mn_ - __builtin_amdgcn_logf(s_) - nd_;                          \
    if (GUARDED) c_ = ((unsigned)(tml + (K)) < 512u) ? c_ : BIGV;              \
    dg = up_; P = c_;                                                          \
    if (doring) ring[w][(tb64 + (K)) & 63] = c_;                               \
  }

#define DP16(G)                                                                \
    DPSTEP(0,  cur0.x, 0, rg0.x, G) DPSTEP(1,  cur0.x, 1, rg0.y, G)            \
    DPSTEP(2,  cur0.y, 0, rg0.z, G) DPSTEP(3,  cur0.y, 1, rg0.w, G)            \
    DPSTEP(4,  cur1.x, 0, rg1.x, G) DPSTEP(5,  cur1.x, 1, rg1.y, G)            \
    DPSTEP(6,  cur1.y, 0, rg1.z, G) DPSTEP(7,  cur1.y, 1, rg1.w, G)            \
    DPSTEP(8,  cur2.x, 0, rg2.x, G) DPSTEP(9,  cur2.x, 1, rg2.y, G)            \
    DPSTEP(10, cur2.y, 0, rg2.z, G) DPSTEP(11, cur2.y, 1, rg2.w, G)            \
    DPSTEP(12, cur3.x, 0, rg3.x, G) DPSTEP(13, cur3.x, 1, rg3.y, G)            \
    DPSTEP(14, cur3.y, 0, rg3.z, G) DPSTEP(15, cur3.y, 1, rg3.w, G)

  for (int p = 0; p < 70; ++p) {
    const int pw = p - 5 * w;
    if ((unsigned)pw < 36u) {
      const int tb   = 16 * pw + 1;
      const int tml  = tb - l - 1;
      const int tb64 = tb - 64;
      const int wi   = (w > 0) ? (w - 1) : 0;
      const float4* rpq = (const float4*)(&ring[wi][0]);
      const int rb = 4 * (pw & 3);
      const float4 rg0 = rpq[rb], rg1 = rpq[rb+1], rg2 = rpq[rb+2], rg3 = rpq[rb+3];
      if constexpr (PRE) {
        const int gb = 4 * pw + 4;
        nxt0 = rp[min(max(gb + 0 - lq, 0), 128)];
        nxt1 = rp[min(max(gb + 1 - lq, 0), 128)];
        nxt2 = rp[min(max(gb + 2 - lq, 0), 128)];
        nxt3 = rp[min(max(gb + 3 - lq, 0), 128)];
      }
      if ((unsigned)(pw - 4) < 28u) {
        DP16(false)
      } else {
        DP16(true)
      }
      if constexpr (PRE) { cur0 = nxt0; cur1 = nxt1; cur2 = nxt2; cur3 = nxt3; }
    }
    __builtin_amdgcn_sched_barrier(0);
    asm volatile("s_waitcnt lgkmcnt(0)" ::: "memory");
    __builtin_amdgcn_s_barrier();
    __builtin_amdgcn_sched_barrier(0);
  }

  // peel: wave 7's pw = 35 (tb = 561), steps t = 561..575 only (skip t = 576)
  if (w == 7) {
    const int tb   = 561;
    const int tml  = tb - l - 1;
    const int tb64 = tb - 64;
    const float4* rpq = (const float4*)(&ring[6][0]);
    const int rb = 4 * (35 & 3);
    const float4 rg0 = rpq[rb], rg1 = rpq[rb+1], rg2 = rpq[rb+2], rg3 = rpq[rb+3];
    DPSTEP(0,  cur0.x, 0, rg0.x, true) DPSTEP(1,  cur0.x, 1, rg0.y, true)
    DPSTEP(2,  cur0.y, 0, rg0.z, true) DPSTEP(3,  cur0.y, 1, rg0.w, true)
    DPSTEP(4,  cur1.x, 0, rg1.x, true) DPSTEP(5,  cur1.x, 1, rg1.y, true)
    DPSTEP(6,  cur1.y, 0, rg1.z, true) DPSTEP(7,  cur1.y, 1, rg1.w, true)
    DPSTEP(8,  cur2.x, 0, rg2.x, true) DPSTEP(9,  cur2.x, 1, rg2.y, true)
    DPSTEP(10, cur2.y, 0, rg2.z, true) DPSTEP(11, cur2.y, 1, rg2.w, true)
    DPSTEP(12, cur3.x, 0, rg3.x, true) DPSTEP(13, cur3.x, 1, rg3.y, true)
    DPSTEP(14, cur3.y, 0, rg3.z, true)
  }
#undef DP16
#undef DPSTEP

  if (tid == 511) out[b] = P * LN2f;   // P = r'(512,512) in log2 units
}

extern "C" void kernel_launch(void* const* d_in, const int* in_sizes, int n_in,
                              void* d_out, int out_size, void* d_ws, size_t ws_size,
                              hipStream_t stream)
{
  const float* x = (const float*)d_in[0];
  const float* y = (const float*)d_in[1];
  float* o = (float*)d_out;
  const size_t need = (size_t)64 * 512 * 516 * 2;   // 33,816,576 B
  if (ws_size >= need) {
    unsigned short* nd = (unsigned short*)d_ws;
    dist_kernel<<<dim3(64, 8), 256, 0, stream>>>(x, y, nd);
    dp_kernel<true><<<64, 512, 0, stream>>>(nd, x, y, o);
  } else {
    dp_kernel<false><<<64, 512, 0, stream>>>(nullptr, x, y, o);
  }
}